// Round 8
// baseline (116.760 us; speedup 1.0000x reference)
//
#include <hip/hip_runtime.h>
#include <math.h>

// VectorQuantizer — bit-exact emulation of the numpy fp32 reference (proven R2-R11):
//   d[n,k] = fl32( fl32(x2[n]+c2[k]) - fl32(2 * fl32(exact_fp64_dot)) ), first argmin.
//
// R20: single fused kernel, no workspace. R19's profile: main kernel <43us
// (out of top-5); harness 268MB fills (44us) + setup launch + gaps dominate.
// Fuse setup into the block:
//   * per-block in-register B hi-frags built straight from cb with the SAME
//     lane layout the setup kernel wrote (R13-verified):
//       Bh[t][kk][j] = (f16)cb[(wid*8+t)*16+(lane&15)][kk*32+(lane>>4)*8+j]
//     32 dwordx4 L2 loads/thread issued under the x-stage HBM latency.
//   * per-block s_c2 via the exact streaming form of np_pairwise_sum64
//     (identical op order/rounding, R2-proven); resolver reads s_c2 (same bits).
//   * setup kernel, bhT/c2 globals, hasT branch, fallback kernel: deleted.
// Skeleton, A-build, adaptive THR (R18 proof), two-phase deterministic filter,
// candidate list, verbatim fp64 resolver, output: R19-verbatim (absmax=0).

#define N_CODES   512
#define CODE_DIM  64
#define CH_STRIDE 4096                      // floats between channels
#define B_STRIDE  (CODE_DIM * CH_STRIDE)    // floats between batches
#define XPITCH    68                        // xs row pitch (mult of 4)
#define CAP       256                       // candidate-list capacity

typedef _Float16 f16x8 __attribute__((ext_vector_type(8)));
typedef float    f32x4 __attribute__((ext_vector_type(4)));

__device__ __forceinline__ unsigned short f16_bits(_Float16 h) {
    union { _Float16 f; unsigned short u; } cv; cv.f = h; return cv.u;
}

__device__ __forceinline__ uint4 pack8u16(const unsigned short* s) {
    uint4 v;
    v.x = (unsigned)s[0] | ((unsigned)s[1] << 16);
    v.y = (unsigned)s[2] | ((unsigned)s[3] << 16);
    v.z = (unsigned)s[4] | ((unsigned)s[5] << 16);
    v.w = (unsigned)s[6] | ((unsigned)s[7] << 16);
    return v;
}

// Rare-path exact resolver — VERBATIM R12 arithmetic (bit-exact proven):
// reads only LDS (xs, s_x2e, s_c2, s_res) and global (cb). __noinline__,
// one hot call site; caller has no live register arrays across the call.
__device__ __noinline__ void resolve_cell(const float* __restrict__ cb,
                                          const float* c2s,          // s_c2 (LDS)
                                          const float* xs_base,      // &xs[0][0]
                                          const float* s_x2e,
                                          unsigned long long* s_res,
                                          int row, int k) {
    const float* crow = cb + (size_t)k * CODE_DIM;
    double b0 = 0.0, b1 = 0.0, b2 = 0.0, b3 = 0.0;
#pragma unroll
    for (int c = 0; c < CODE_DIM; c += 4) {
        b0 = fma((double)crow[c + 0], (double)xs_base[(c + 0) * XPITCH + row], b0);
        b1 = fma((double)crow[c + 1], (double)xs_base[(c + 1) * XPITCH + row], b1);
        b2 = fma((double)crow[c + 2], (double)xs_base[(c + 2) * XPITCH + row], b2);
        b3 = fma((double)crow[c + 3], (double)xs_base[(c + 3) * XPITCH + row], b3);
    }
    const double dot64 = (b0 + b1) + (b2 + b3);
    const float  ein   = (float)dot64;
    const float  tmp   = __fadd_rn(s_x2e[row], c2s[k]);
    const float  dk    = __fsub_rn(tmp, __fmul_rn(2.0f, ein));
    const unsigned u     = __float_as_uint(dk);
    const unsigned key32 = (u & 0x80000000u) ? ~u : (u | 0x80000000u);
    atomicMin(&s_res[row], ((unsigned long long)key32 << 32) | (unsigned)k);
}

// ---------------- fused: setup + 4-wave hi-only MFMA filter + resolve -------
// Block = one (b,h) group: 64 rows x 512 codes, 256 threads (4 waves).
// Wave wid: ALL 64 rows (4 M-tiles) x codes [wid*128, wid*128+128) (8 N-tiles).
__global__ __launch_bounds__(256, 2)
void vq_fused_kernel(const float* __restrict__ in,
                     const float* __restrict__ cb,
                     float* __restrict__ out) {
    __shared__ __align__(16) float xs[CODE_DIM][XPITCH];      // x-tile [dim][row], 17.4KB
    __shared__ __align__(16) unsigned short aHi[4][2][512];   // A-frags hi, 8KB
    __shared__ float s_c2[N_CODES];                           // numpy-exact c2, 2KB
    __shared__ float s_wm[4][64];                             // per-wave row mins
    __shared__ float s_lim[64];                               // row min + THR_row
    __shared__ float s_thr[64];                               // 4e-5*sqrt(x2)+1e-4
    __shared__ float s_x2e[64];                               // numpy-exact x2 per row
    __shared__ int   s_cnt[64];                               // candidates per row
    __shared__ int   s_win[64];                               // sole candidate (cnt==1)
    __shared__ int   s_ncand;
    __shared__ int   s_cand[CAP];                             // packed (row<<16)|code
    __shared__ unsigned long long s_res[64];                  // packed (dk-key, k)

    const int tid  = threadIdx.x;
    const int lane = tid & 63;
    const int wid  = tid >> 6;               // 0..3
    const int gw   = blockIdx.x;             // (b,h) group 0..1023
    const float* src = in + (size_t)(gw >> 6) * B_STRIDE + (size_t)(gw & 63) * 64;

    // --- stage x-tile FIRST (HBM, longest pole): xs[c][r] = src[c*4096+r] ---
#pragma unroll
    for (int i = 0; i < 4; ++i) {
        const int s = tid + (i << 8);
        const int c = s >> 4, q = s & 15;
        *(float4*)&xs[c][q * 4] = *(const float4*)(src + (size_t)c * CH_STRIDE + q * 4);
    }

    // --- in-register B hi-frags straight from cb (L2-resident, hides under
    //     the x-stage). Layout == R13-verified setup table:
    //     Bh[t][kk][j] = (f16)cb[(wid*8+t)*16+(lane&15)][kk*32+(lane>>4)*8+j]
    f16x8 Bh[8][2];
#pragma unroll
    for (int t = 0; t < 8; ++t) {
        const int code = (((wid << 3) + t) << 4) + (lane & 15);
        const float* cr = cb + (size_t)code * CODE_DIM + ((lane >> 4) << 3);
#pragma unroll
        for (int kk = 0; kk < 2; ++kk) {
            const float4 f0 = *(const float4*)(cr + (kk << 5));
            const float4 f1 = *(const float4*)(cr + (kk << 5) + 4);
            f16x8 b;
            b[0] = (_Float16)f0.x; b[1] = (_Float16)f0.y;
            b[2] = (_Float16)f0.z; b[3] = (_Float16)f0.w;
            b[4] = (_Float16)f1.x; b[5] = (_Float16)f1.y;
            b[6] = (_Float16)f1.z; b[7] = (_Float16)f1.w;
            Bh[t][kk] = b;
        }
    }

    // --- per-block c2: streaming np_pairwise_sum64 (identical op order to
    //     the R2-proven setup kernel: mul_rn then fadd_rn, rolling 8-acc) ---
#pragma unroll
    for (int cc = 0; cc < 2; ++cc) {
        const int code = tid + (cc << 8);
        const float* cr = cb + (size_t)code * CODE_DIM;
        float r[8];
#pragma unroll
        for (int j = 0; j < 8; ++j) r[j] = __fmul_rn(cr[j], cr[j]);
#pragma unroll
        for (int i = 8; i < 64; i += 8) {
#pragma unroll
            for (int j = 0; j < 8; ++j)
                r[j] = __fadd_rn(r[j], __fmul_rn(cr[i + j], cr[i + j]));
        }
        s_c2[code] = __fadd_rn(
            __fadd_rn(__fadd_rn(r[0], r[1]), __fadd_rn(r[2], r[3])),
            __fadd_rn(__fadd_rn(r[4], r[5]), __fadd_rn(r[6], r[7])));
    }

    if (tid < 64) { s_cnt[tid] = 0; s_res[tid] = ~0ull; }
    if (tid == 0) s_ncand = 0;
    __syncthreads();

    // --- numpy-exact x2 per row (R5-proven order) + per-row THR -------------
    if (tid < 64) {
        float r[8];
#pragma unroll
        for (int j = 0; j < 8; ++j) r[j] = __fmul_rn(xs[j][tid], xs[j][tid]);
#pragma unroll
        for (int i = 8; i < 64; i += 8) {
#pragma unroll
            for (int j = 0; j < 8; ++j)
                r[j] = __fadd_rn(r[j], __fmul_rn(xs[i + j][tid], xs[i + j][tid]));
        }
        const float x2 = __fadd_rn(
            __fadd_rn(__fadd_rn(r[0], r[1]), __fadd_rn(r[2], r[3])),
            __fadd_rn(__fadd_rn(r[4], r[5]), __fadd_rn(r[6], r[7])));
        s_x2e[tid] = x2;
        // per-row adaptive threshold: 2*err bound (err <= 1.53e-5*sqrt(x2)
        // + ~1.7e-5) with >=2.6x margin (R18-proven, absmax=0).
        s_thr[tid] = __fmaf_rn(4.0e-5f, sqrtf(x2), 1.0e-4f);
    }

    // --- shared A-frag build (hi only): once per block, 8 planes / 256 thr --
    // plane p = tid>>6 .. +4: (mt=p>>1, kk=p&1); slot l=tid&63:
    // row = mt*16+(l&15), d = kk*32+(l>>4)*8+j   (R13-verified layout)
#pragma unroll
    for (int pp = 0; pp < 2; ++pp) {
        const int p  = (tid >> 6) + (pp << 2);
        const int mt = p >> 1, kk = p & 1;
        const int l  = tid & 63;
        const int row = (mt << 4) + (l & 15);
        const int d0  = (kk << 5) + ((l >> 4) << 3);
        unsigned short hs[8];
#pragma unroll
        for (int j = 0; j < 8; ++j)
            hs[j] = f16_bits((_Float16)xs[d0 + j][row]);
        *(uint4*)&aHi[mt][kk][l * 8] = pack8u16(hs);
    }
    __syncthreads();

    // --- A-frags to registers: 8 conflict-free ds_read_b128 per thread ------
    f16x8 Ah[4][2];
#pragma unroll
    for (int mt = 0; mt < 4; ++mt)
#pragma unroll
        for (int kk = 0; kk < 2; ++kk)
            Ah[mt][kk] = *(const f16x8*)&aHi[mt][kk][lane * 8];

    const int nsub  = lane & 15;
    const int rbase = (lane >> 4) << 2;      // row-in-tile base for D-layout

    // --- phase 1: full scan, row-min only (load-free: B in registers) -------
    float rm[16];                            // [mt*4+r] rows mt*16+rbase+r
#pragma unroll
    for (int i = 0; i < 16; ++i) rm[i] = 1e30f;
#pragma unroll
    for (int t = 0; t < 8; ++t) {
        const float c2v = s_c2[((((wid << 3) + t)) << 4) + nsub];
#pragma unroll
        for (int mt = 0; mt < 4; ++mt) {
            f32x4 a1 = {0.f, 0.f, 0.f, 0.f};
            a1 = __builtin_amdgcn_mfma_f32_16x16x32_f16(Ah[mt][0], Bh[t][0], a1, 0, 0, 0);
            a1 = __builtin_amdgcn_mfma_f32_16x16x32_f16(Ah[mt][1], Bh[t][1], a1, 0, 0, 0);
#pragma unroll
            for (int r = 0; r < 4; ++r) {
                const float v = __fmaf_rn(-2.0f, a1[r], c2v);
                rm[(mt << 2) + r] = fminf(rm[(mt << 2) + r], v);
            }
        }
    }

    // --- row min over the 16 code-lanes of each group -----------------------
#pragma unroll
    for (int s = 1; s < 16; s <<= 1)
#pragma unroll
        for (int i = 0; i < 16; ++i) rm[i] = fminf(rm[i], __shfl_xor(rm[i], s, 64));
    if (nsub == 0) {
#pragma unroll
        for (int mt = 0; mt < 4; ++mt)
#pragma unroll
            for (int r = 0; r < 4; ++r)
                s_wm[wid][(mt << 4) + rbase + r] = rm[(mt << 2) + r];
    }
    __syncthreads();
    if (tid < 64) {
        float m = s_wm[0][tid];
#pragma unroll
        for (int w = 1; w < 4; ++w) m = fminf(m, s_wm[w][tid]);
        s_lim[tid] = m + s_thr[tid];
    }
    __syncthreads();

    // lane-local lims for its 16 rows
    float lim[16];
#pragma unroll
    for (int mt = 0; mt < 4; ++mt)
#pragma unroll
        for (int r = 0; r < 4; ++r)
            lim[(mt << 2) + r] = s_lim[(mt << 4) + rbase + r];

    // --- phase 2: bit-identical recompute from in-reg B, collect candidates -
#pragma unroll
    for (int t = 0; t < 8; ++t) {
        const int Tg = (wid << 3) + t;
        const float c2v = s_c2[(Tg << 4) + nsub];
#pragma unroll
        for (int mt = 0; mt < 4; ++mt) {
            f32x4 a1 = {0.f, 0.f, 0.f, 0.f};
            a1 = __builtin_amdgcn_mfma_f32_16x16x32_f16(Ah[mt][0], Bh[t][0], a1, 0, 0, 0);
            a1 = __builtin_amdgcn_mfma_f32_16x16x32_f16(Ah[mt][1], Bh[t][1], a1, 0, 0, 0);
#pragma unroll
            for (int r = 0; r < 4; ++r) {
                const float v = __fmaf_rn(-2.0f, a1[r], c2v);
                if (v <= lim[(mt << 2) + r]) {        // deterministic == phase-1
                    const int row  = (mt << 4) + rbase + r;
                    const int code = (Tg << 4) + nsub;
                    atomicAdd(&s_cnt[row], 1);
                    s_win[row] = code;                // sole writer iff cnt==1
                    const int slot = atomicAdd(&s_ncand, 1);
                    if (slot < CAP) s_cand[slot] = (row << 16) | code;
                }
            }
        }
    }
    __syncthreads();

    // --- resolve: ONE call site, thread-parallel over the candidate list ----
    const int nc = s_ncand;
    const int ne = nc < CAP ? nc : CAP;
    for (int e = tid; e < ne; e += 256) {
        const int row = s_cand[e] >> 16;
        const int k   = s_cand[e] & 0xFFFF;
        if (s_cnt[row] > 1)
            resolve_cell(cb, s_c2, &xs[0][0], s_x2e, s_res, row, k);
    }
    if (nc > CAP) {                               // pathological-tie fallback
#pragma unroll 1
        for (int row = wid; row < 64; row += 4)
            if (s_cnt[row] > 1)
#pragma unroll 1
                for (int k = lane; k < N_CODES; k += 64)
                    resolve_cell(cb, s_c2, &xs[0][0], s_x2e, s_res, row, k);
    }
    __syncthreads();

    // --- output: wave wid writes rows wid*16..+15 (coalesced 256B each) -----
    const size_t n0 = (size_t)gw * 64;
#pragma unroll
    for (int rr = 0; rr < 16; ++rr) {
        const int row = (wid << 4) + rr;
        const int idx = (s_cnt[row] == 1) ? s_win[row]
                                          : (int)(s_res[row] & 0xFFFFFFFFull);
        out[(n0 + row) * CODE_DIM + lane] = cb[(size_t)idx * CODE_DIM + lane];
    }
}

extern "C" void kernel_launch(void* const* d_in, const int* in_sizes, int n_in,
                              void* d_out, int out_size, void* d_ws, size_t ws_size,
                              hipStream_t stream) {
    const float* in  = (const float*)d_in[0];   // (16,64,64,64) fp32
    const float* cb  = (const float*)d_in[1];   // (512,64) fp32
    float*       out = (float*)d_out;           // (16,64,64,64) fp32
    (void)d_ws; (void)ws_size;                  // workspace no longer needed

    // Single fused launch: 1024 blocks = one (b,h) group (64 rows) each.
    vq_fused_kernel<<<dim3(1024), dim3(256), 0, stream>>>(in, cb, out);
}

// Round 9
// 99.339 us; speedup vs baseline: 1.1754x; 1.1754x over previous
//
#include <hip/hip_runtime.h>
#include <math.h>

// VectorQuantizer — bit-exact emulation of the numpy fp32 reference (proven R2-R11):
//   d[n,k] = fl32( fl32(x2[n]+c2[k]) - fl32(2 * fl32(exact_fp64_dot)) ), first argmin.
//
// R21 = R19 restored verbatim (best: 98.75us total, absmax=0). R20's fusion
// regressed (+18us): per-block B/c2 rebuild put ~500 VALU + 160 L2 loads per
// thread on the pre-barrier critical path (c2-build alone re-read the whole
// 128KB cb per block = 128MB aggregate L2 traffic) to save a ~2us setup
// launch. Budget at R19: harness fill ~44us (not controllable) + setup ~2us
// + main kernel ~40us latency-bound with all pipes <25% busy.
//
// R19's design (on top of R15/R17/R18, each step absmax=0-verified):
//   * B hi-frags prefetched to REGISTERS at kernel top; phase 1 load-free;
//     phase 2 reuses in-reg B (bit-identical recompute).
//   * hi-only f16 filter + per-row adaptive threshold (R18 proof):
//     THR_row = 4e-5*sqrt(x2) + 1e-4 >= 2.6x the rigorous error bound.
//   * shared A-frag build once per block; c2 staged in LDS.
//   * two-phase deterministic filter -> candidate list -> ONE-call-site
//     verbatim-R12 fp64 resolver for ambiguous rows only.

#define N_CODES   512
#define CODE_DIM  64
#define CH_STRIDE 4096                      // floats between channels
#define B_STRIDE  (CODE_DIM * CH_STRIDE)    // floats between batches
#define XPITCH    68                        // xs row pitch (mult of 4)
#define CAP       256                       // candidate-list capacity

typedef _Float16 f16x8 __attribute__((ext_vector_type(8)));
typedef float    f32x4 __attribute__((ext_vector_type(4)));

__device__ __forceinline__ unsigned short f16_bits(_Float16 h) {
    union { _Float16 f; unsigned short u; } cv; cv.f = h; return cv.u;
}

__device__ __forceinline__ uint4 pack8u16(const unsigned short* s) {
    uint4 v;
    v.x = (unsigned)s[0] | ((unsigned)s[1] << 16);
    v.y = (unsigned)s[2] | ((unsigned)s[3] << 16);
    v.z = (unsigned)s[4] | ((unsigned)s[5] << 16);
    v.w = (unsigned)s[6] | ((unsigned)s[7] << 16);
    return v;
}

// ---------------- setup: c2 (numpy pairwise) + f16-hi B-frag table ----------
__device__ __forceinline__ float np_pairwise_sum64(const float* a) {
    float r[8];
#pragma unroll
    for (int j = 0; j < 8; ++j) r[j] = a[j];
#pragma unroll
    for (int i = 8; i < 64; i += 8) {
#pragma unroll
        for (int j = 0; j < 8; ++j) r[j] = __fadd_rn(r[j], a[i + j]);
    }
    return __fadd_rn(__fadd_rn(__fadd_rn(r[0], r[1]), __fadd_rn(r[2], r[3])),
                     __fadd_rn(__fadd_rn(r[4], r[5]), __fadd_rn(r[6], r[7])));
}

// B-frag table in exact MFMA B-operand order (16x16x32: n=lane&15,
// k=(lane>>4)*8+j): element index ((T*2+kk)*64 + lane)*8 + j  maps to
// cb[T*16 + (lane&15)][kk*32 + (lane>>4)*8 + j].  (verified: R13-R19 absmax=0)
__global__ void vq_setup_kernel(const float* __restrict__ cb, float* __restrict__ c2,
                                unsigned short* __restrict__ bh, int buildT) {
    const int t = blockIdx.x * blockDim.x + threadIdx.x;   // 64 blocks x 64 = 4096
    if (buildT) {
        const int l    = t & 63;
        const int kkT  = t >> 6;                           // T*2+kk, 0..63
        const int code = (kkT >> 1) * 16 + (l & 15);
        const int d0   = (kkT & 1) * 32 + ((l >> 4) << 3);
        const float* crow = cb + code * CODE_DIM + d0;
        unsigned short hs[8];
#pragma unroll
        for (int j = 0; j < 8; ++j) hs[j] = f16_bits((_Float16)crow[j]);   // RNE
        *(uint4*)(bh + (size_t)t * 8) = pack8u16(hs);
    }
    if (t < N_CODES) {
        const float* row = cb + t * CODE_DIM;
        float sq[CODE_DIM];
#pragma unroll
        for (int j = 0; j < CODE_DIM; ++j) sq[j] = __fmul_rn(row[j], row[j]);
        c2[t] = np_pairwise_sum64(sq);
    }
}

// Rare-path exact resolver — VERBATIM R12 arithmetic (bit-exact proven):
// reads only LDS (xs, s_x2e, s_res) and global (cb, c2). __noinline__, one
// hot call site; caller has no live register arrays across the call.
__device__ __noinline__ void resolve_cell(const float* __restrict__ cb,
                                          const float* __restrict__ c2g,
                                          const float* xs_base,      // &xs[0][0]
                                          const float* s_x2e,
                                          unsigned long long* s_res,
                                          int row, int k) {
    const float* crow = cb + (size_t)k * CODE_DIM;
    double b0 = 0.0, b1 = 0.0, b2 = 0.0, b3 = 0.0;
#pragma unroll
    for (int c = 0; c < CODE_DIM; c += 4) {
        b0 = fma((double)crow[c + 0], (double)xs_base[(c + 0) * XPITCH + row], b0);
        b1 = fma((double)crow[c + 1], (double)xs_base[(c + 1) * XPITCH + row], b1);
        b2 = fma((double)crow[c + 2], (double)xs_base[(c + 2) * XPITCH + row], b2);
        b3 = fma((double)crow[c + 3], (double)xs_base[(c + 3) * XPITCH + row], b3);
    }
    const double dot64 = (b0 + b1) + (b2 + b3);
    const float  ein   = (float)dot64;
    const float  tmp   = __fadd_rn(s_x2e[row], c2g[k]);
    const float  dk    = __fsub_rn(tmp, __fmul_rn(2.0f, ein));
    const unsigned u     = __float_as_uint(dk);
    const unsigned key32 = (u & 0x80000000u) ? ~u : (u | 0x80000000u);
    atomicMin(&s_res[row], ((unsigned long long)key32 << 32) | (unsigned)k);
}

// ---------------- main: 4-wave hi-only MFMA filter + exact resolve ----------
// Block = one (b,h) group: 64 rows x 512 codes, 256 threads (4 waves).
// Wave wid: ALL 64 rows (4 M-tiles) x codes [wid*128, wid*128+128) (8 N-tiles).
__global__ __launch_bounds__(256, 2)
void vq_block_kernel(const float* __restrict__ in,
                     const float* __restrict__ cb,
                     const float* __restrict__ c2g,
                     const unsigned short* __restrict__ bhT,
                     float* __restrict__ out) {
    __shared__ __align__(16) float xs[CODE_DIM][XPITCH];      // x-tile [dim][row], 17.4KB
    __shared__ __align__(16) unsigned short aHi[4][2][512];   // A-frags hi, 8KB
    __shared__ float s_c2[N_CODES];                           // c2 staged, 2KB
    __shared__ float s_wm[4][64];                             // per-wave row mins
    __shared__ float s_lim[64];                               // row min + THR_row
    __shared__ float s_thr[64];                               // 4e-5*sqrt(x2)+1e-4
    __shared__ float s_x2e[64];                               // numpy-exact x2 per row
    __shared__ int   s_cnt[64];                               // candidates per row
    __shared__ int   s_win[64];                               // sole candidate (cnt==1)
    __shared__ int   s_ncand;
    __shared__ int   s_cand[CAP];                             // packed (row<<16)|code
    __shared__ unsigned long long s_res[64];                  // packed (dk-key, k)

    const int tid  = threadIdx.x;
    const int lane = tid & 63;
    const int wid  = tid >> 6;               // 0..3
    const int gw   = blockIdx.x;             // (b,h) group 0..1023
    const float* src = in + (size_t)(gw >> 6) * B_STRIDE + (size_t)(gw & 63) * 64;

    // --- B prefetch: all 16 hi-frags for this wave's 8 N-tiles, to REGISTERS.
    //     Independent of LDS -> L2 latency hides under staging + A-build; the
    //     SAME registers serve phase 1 and phase 2 (no reloads).
    f16x8 Bh[8][2];
#pragma unroll
    for (int t = 0; t < 8; ++t) {
        const int T2 = (((wid << 3) + t) << 1);
        Bh[t][0] = *(const f16x8*)(bhT + ((size_t)(T2 + 0) * 64 + lane) * 8);
        Bh[t][1] = *(const f16x8*)(bhT + ((size_t)(T2 + 1) * 64 + lane) * 8);
    }

    // --- stage x-tile: xs[c][r] = src[c*4096 + r]; float4 slots, coalesced --
#pragma unroll
    for (int i = 0; i < 4; ++i) {
        const int s = tid + (i << 8);
        const int c = s >> 4, q = s & 15;
        *(float4*)&xs[c][q * 4] = *(const float4*)(src + (size_t)c * CH_STRIDE + q * 4);
    }
    // stage c2 into LDS (coalesced)
    s_c2[tid]       = c2g[tid];
    s_c2[tid + 256] = c2g[tid + 256];
    if (tid < 64) { s_cnt[tid] = 0; s_res[tid] = ~0ull; }
    if (tid == 0) s_ncand = 0;
    __syncthreads();

    // --- numpy-exact x2 per row (R5-proven order) + per-row THR -------------
    if (tid < 64) {
        float r[8];
#pragma unroll
        for (int j = 0; j < 8; ++j) r[j] = __fmul_rn(xs[j][tid], xs[j][tid]);
#pragma unroll
        for (int i = 8; i < 64; i += 8) {
#pragma unroll
            for (int j = 0; j < 8; ++j)
                r[j] = __fadd_rn(r[j], __fmul_rn(xs[i + j][tid], xs[i + j][tid]));
        }
        const float x2 = __fadd_rn(
            __fadd_rn(__fadd_rn(r[0], r[1]), __fadd_rn(r[2], r[3])),
            __fadd_rn(__fadd_rn(r[4], r[5]), __fadd_rn(r[6], r[7])));
        s_x2e[tid] = x2;
        // per-row adaptive threshold: 2*err bound (err <= 1.53e-5*sqrt(x2)
        // + ~1.7e-5) with >=2.6x margin (R18-proven, absmax=0).
        s_thr[tid] = __fmaf_rn(4.0e-5f, sqrtf(x2), 1.0e-4f);
    }

    // --- shared A-frag build (hi only): once per block, 8 planes / 256 thr --
    // plane p = tid>>6 .. +4: (mt=p>>1, kk=p&1); slot l=tid&63:
    // row = mt*16+(l&15), d = kk*32+(l>>4)*8+j   (R13-verified layout)
#pragma unroll
    for (int pp = 0; pp < 2; ++pp) {
        const int p  = (tid >> 6) + (pp << 2);
        const int mt = p >> 1, kk = p & 1;
        const int l  = tid & 63;
        const int row = (mt << 4) + (l & 15);
        const int d0  = (kk << 5) + ((l >> 4) << 3);
        unsigned short hs[8];
#pragma unroll
        for (int j = 0; j < 8; ++j)
            hs[j] = f16_bits((_Float16)xs[d0 + j][row]);
        *(uint4*)&aHi[mt][kk][l * 8] = pack8u16(hs);
    }
    __syncthreads();

    // --- A-frags to registers: 8 conflict-free ds_read_b128 per thread ------
    f16x8 Ah[4][2];
#pragma unroll
    for (int mt = 0; mt < 4; ++mt)
#pragma unroll
        for (int kk = 0; kk < 2; ++kk)
            Ah[mt][kk] = *(const f16x8*)&aHi[mt][kk][lane * 8];

    const int nsub  = lane & 15;
    const int rbase = (lane >> 4) << 2;      // row-in-tile base for D-layout

    // --- phase 1: full scan, row-min only (load-free: B in registers) -------
    float rm[16];                            // [mt*4+r] rows mt*16+rbase+r
#pragma unroll
    for (int i = 0; i < 16; ++i) rm[i] = 1e30f;
#pragma unroll
    for (int t = 0; t < 8; ++t) {
        const float c2v = s_c2[((((wid << 3) + t)) << 4) + nsub];
#pragma unroll
        for (int mt = 0; mt < 4; ++mt) {
            f32x4 a1 = {0.f, 0.f, 0.f, 0.f};
            a1 = __builtin_amdgcn_mfma_f32_16x16x32_f16(Ah[mt][0], Bh[t][0], a1, 0, 0, 0);
            a1 = __builtin_amdgcn_mfma_f32_16x16x32_f16(Ah[mt][1], Bh[t][1], a1, 0, 0, 0);
#pragma unroll
            for (int r = 0; r < 4; ++r) {
                const float v = __fmaf_rn(-2.0f, a1[r], c2v);
                rm[(mt << 2) + r] = fminf(rm[(mt << 2) + r], v);
            }
        }
    }

    // --- row min over the 16 code-lanes of each group -----------------------
#pragma unroll
    for (int s = 1; s < 16; s <<= 1)
#pragma unroll
        for (int i = 0; i < 16; ++i) rm[i] = fminf(rm[i], __shfl_xor(rm[i], s, 64));
    if (nsub == 0) {
#pragma unroll
        for (int mt = 0; mt < 4; ++mt)
#pragma unroll
            for (int r = 0; r < 4; ++r)
                s_wm[wid][(mt << 4) + rbase + r] = rm[(mt << 2) + r];
    }
    __syncthreads();
    if (tid < 64) {
        float m = s_wm[0][tid];
#pragma unroll
        for (int w = 1; w < 4; ++w) m = fminf(m, s_wm[w][tid]);
        s_lim[tid] = m + s_thr[tid];
    }
    __syncthreads();

    // lane-local lims for its 16 rows
    float lim[16];
#pragma unroll
    for (int mt = 0; mt < 4; ++mt)
#pragma unroll
        for (int r = 0; r < 4; ++r)
            lim[(mt << 2) + r] = s_lim[(mt << 4) + rbase + r];

    // --- phase 2: bit-identical recompute from in-reg B, collect candidates -
#pragma unroll
    for (int t = 0; t < 8; ++t) {
        const int Tg = (wid << 3) + t;
        const float c2v = s_c2[(Tg << 4) + nsub];
#pragma unroll
        for (int mt = 0; mt < 4; ++mt) {
            f32x4 a1 = {0.f, 0.f, 0.f, 0.f};
            a1 = __builtin_amdgcn_mfma_f32_16x16x32_f16(Ah[mt][0], Bh[t][0], a1, 0, 0, 0);
            a1 = __builtin_amdgcn_mfma_f32_16x16x32_f16(Ah[mt][1], Bh[t][1], a1, 0, 0, 0);
#pragma unroll
            for (int r = 0; r < 4; ++r) {
                const float v = __fmaf_rn(-2.0f, a1[r], c2v);
                if (v <= lim[(mt << 2) + r]) {        // deterministic == phase-1
                    const int row  = (mt << 4) + rbase + r;
                    const int code = (Tg << 4) + nsub;
                    atomicAdd(&s_cnt[row], 1);
                    s_win[row] = code;                // sole writer iff cnt==1
                    const int slot = atomicAdd(&s_ncand, 1);
                    if (slot < CAP) s_cand[slot] = (row << 16) | code;
                }
            }
        }
    }
    __syncthreads();

    // --- resolve: ONE call site, thread-parallel over the candidate list ----
    const int nc = s_ncand;
    const int ne = nc < CAP ? nc : CAP;
    for (int e = tid; e < ne; e += 256) {
        const int row = s_cand[e] >> 16;
        const int k   = s_cand[e] & 0xFFFF;
        if (s_cnt[row] > 1)
            resolve_cell(cb, c2g, &xs[0][0], s_x2e, s_res, row, k);
    }
    if (nc > CAP) {                               // pathological-tie fallback
#pragma unroll 1
        for (int row = wid; row < 64; row += 4)
            if (s_cnt[row] > 1)
#pragma unroll 1
                for (int k = lane; k < N_CODES; k += 64)
                    resolve_cell(cb, c2g, &xs[0][0], s_x2e, s_res, row, k);
    }
    __syncthreads();

    // --- output: wave wid writes rows wid*16..+15 (coalesced 256B each) -----
    const size_t n0 = (size_t)gw * 64;
#pragma unroll
    for (int rr = 0; rr < 16; ++rr) {
        const int row = (wid << 4) + rr;
        const int idx = (s_cnt[row] == 1) ? s_win[row]
                                          : (int)(s_res[row] & 0xFFFFFFFFull);
        out[(n0 + row) * CODE_DIM + lane] = cb[(size_t)idx * CODE_DIM + lane];
    }
}

// ---------------- fallback (R9, proven 190us) if ws too small ---------------
__device__ __forceinline__ float exact_dk_fb(const float* __restrict__ cb,
                                             const float* __restrict__ c2,
                                             const float (&x)[CODE_DIM], float x2, int k) {
    const float* crow = cb + (size_t)k * CODE_DIM;
    double a0 = 0.0, a1 = 0.0, a2 = 0.0, a3 = 0.0;
#pragma unroll
    for (int j = 0; j < CODE_DIM; j += 4) {
        a0 = fma((double)crow[j + 0], (double)x[j + 0], a0);
        a1 = fma((double)crow[j + 1], (double)x[j + 1], a1);
        a2 = fma((double)crow[j + 2], (double)x[j + 2], a2);
        a3 = fma((double)crow[j + 3], (double)x[j + 3], a3);
    }
    const double dot = (a0 + a1) + (a2 + a3);
    const float  ein = (float)dot;
    return __fsub_rn(__fadd_rn(x2, c2[k]), __fmul_rn(2.0f, ein));
}

__global__ __launch_bounds__(512, 2)
void vq_fallback_kernel(const float* __restrict__ in, const float* __restrict__ cb,
                        const float* __restrict__ c2, float* __restrict__ out) {
    __shared__ float s_rb[8][64];
    __shared__ int   s_ri[8][64];
    const int tid = threadIdx.x, lane = tid & 63, wid = tid >> 6;
    const int gw = blockIdx.x, b = gw >> 6, h = gw & 63;
    const float* xin = in + (size_t)b * B_STRIDE + (size_t)h * 64 + lane;
    float x[CODE_DIM];
#pragma unroll
    for (int c = 0; c < CODE_DIM; ++c) x[c] = xin[(size_t)c * CH_STRIDE];
    float r[8];
#pragma unroll
    for (int j = 0; j < 8; ++j) r[j] = __fmul_rn(x[j], x[j]);
#pragma unroll
    for (int i = 8; i < 64; i += 8)
#pragma unroll
        for (int j = 0; j < 8; ++j) r[j] = __fadd_rn(r[j], __fmul_rn(x[i + j], x[i + j]));
    const float x2 = __fadd_rn(__fadd_rn(__fadd_rn(r[0], r[1]), __fadd_rn(r[2], r[3])),
                               __fadd_rn(__fadd_rn(r[4], r[5]), __fadd_rn(r[6], r[7])));
    const int k0 = __builtin_amdgcn_readfirstlane(wid) * 64;
    float ex_best = INFINITY; int bi = k0;
#pragma unroll 1
    for (int kk = 0; kk < 64; ++kk) {
        const float dk = exact_dk_fb(cb, c2, x, x2, k0 + kk);
        if (dk < ex_best) { ex_best = dk; bi = k0 + kk; }
    }
    s_rb[wid][lane] = ex_best; s_ri[wid][lane] = bi;
    __syncthreads();
    float fb2 = s_rb[0][lane]; int fi = s_ri[0][lane];
#pragma unroll
    for (int w = 1; w < 8; ++w) {
        if (s_rb[w][lane] < fb2) { fb2 = s_rb[w][lane]; fi = s_ri[w][lane]; }
    }
    const size_t n0 = (size_t)gw * 64;
#pragma unroll 1
    for (int rr = 0; rr < 8; ++rr) {
        const int row = wid * 8 + rr;
        const int idxr = __shfl(fi, row, 64);
        out[(n0 + row) * CODE_DIM + lane] = cb[(size_t)idxr * CODE_DIM + lane];
    }
}

extern "C" void kernel_launch(void* const* d_in, const int* in_sizes, int n_in,
                              void* d_out, int out_size, void* d_ws, size_t ws_size,
                              hipStream_t stream) {
    const float* in  = (const float*)d_in[0];   // (16,64,64,64) fp32
    const float* cb  = (const float*)d_in[1];   // (512,64) fp32
    float*       out = (float*)d_out;           // (16,64,64,64) fp32

    float* c2 = (float*)d_ws;                                    // 2 KB
    unsigned short* bh = (unsigned short*)((char*)d_ws + 2048);  // 64 KB f16-hi frags
    const bool hasT = ws_size >= (size_t)(2048 + 65536);         // 66.5 KB

    vq_setup_kernel<<<dim3(64), dim3(64), 0, stream>>>(cb, c2, bh, hasT ? 1 : 0);
    if (hasT) {
        // 1024 blocks = one (b,h) group (64 rows) each; 256 threads = 4 waves.
        vq_block_kernel<<<dim3(1024), dim3(256), 0, stream>>>(in, cb, c2, bh, out);
    } else {
        vq_fallback_kernel<<<dim3(1024), dim3(512), 0, stream>>>(in, cb, c2, out);
    }
}